// Round 4
// baseline (130.173 us; speedup 1.0000x reference)
//
#include <hip/hip_runtime.h>
#include <math.h>

constexpr int C = 20;   // classes
constexpr int M = 32;   // max GT per image
#define LN2F 0.69314718055994530942f

// d_ws layout: part[(b*nblk + bx)*4 + {0,1,2}] = {cls_sum, reg_sum, num_pos}
// per block. Plain stores — NO atomics (R12/R13 lesson: device-scope atomicAdd
// to 2 cache lines serializes at ~28 cyc each; 11K atomics == 135 us).
//
// Session ledger:
//   R0 127.4  ds_read IoU loop, KPA=1, cls loaded after IoU   <- prior best
//   R1 134.2  readlane loop + KPA=2 + 2x cls prefetch (VGPR>128 cliff)
//   R2 135.6  readlane loop + compaction + 1x prefetch (readlane hazards)
//   R3 129.0  R0 + cls prefetch only (prefetch alone = +1.6 us; kernel is
//             NOT load-latency-stalled, TLP covers it)
// This round: attack the one surviving theory — the IoU loop's 570 LDS-pipe
// cyc/wave (~14 us/CU, on par with the HBM floor). KPA=2 shares each GT's
// ds_read across 2 anchors; garea recomputed from the float4 (2 VALU ops
// replace the b32 read). LDS pipe per anchor: 570 -> 192 cyc. No prefetch,
// no readlane, VGPR stays in the 65-128 occupancy bucket. 128-thread blocks
// keep R0's 3752-block dispatch balance (14.66 blocks/CU, ~2% tail).
__global__ __launch_bounds__(128) void focal_main(
    const float* __restrict__ cls,   // [B,A,C]
    const float* __restrict__ reg,   // [B,A,4]
    const float* __restrict__ anc,   // [A,4]
    const float* __restrict__ ann,   // [B,M,5]
    float* __restrict__ part,
    int A)
{
    __shared__ float4 s_gbox[M];   // {x1,y1,x2,y2}; invalid GT -> zero box (iou=0)
    __shared__ int    s_glbl[M];
    __shared__ float  s_red[2 * 3];

    const int b   = blockIdx.y;
    const int tid = threadIdx.x;

    // ---- stage annotations (validity folded into zero-box) ----
    if (tid < M) {
        const float* ap = ann + (size_t)b * M * 5 + (size_t)tid * 5;
        float x1 = ap[0], y1 = ap[1], x2 = ap[2], y2 = ap[3];
        const float lb = ap[4];
        s_glbl[tid] = (int)lb;
        if (lb == -1.0f) { x1 = 0.f; y1 = 0.f; x2 = 0.f; y2 = 0.f; }
        s_gbox[tid] = make_float4(x1, y1, x2, y2);
    }
    __syncthreads();

    // Two anchors per thread within this block's 256-anchor span.
    const int a0 = blockIdx.x * 256 + tid;
    const int a1 = a0 + 128;
    const bool ok0 = a0 < A;
    const bool ok1 = a1 < A;

    float clsSum = 0.f, regSum = 0.f, posf = 0.f;

    float4 av0 = make_float4(0.f, 0.f, 0.f, 1.f);   // degenerate: area 0
    float4 av1 = av0;
    if (ok0) av0 = *(const float4*)(anc + (size_t)a0 * 4);
    if (ok1) av1 = *(const float4*)(anc + (size_t)a1 * 4);
    const float area0 = (av0.z - av0.x) * (av0.w - av0.y);
    const float area1 = (av1.z - av1.x) * (av1.w - av1.y);

    // ---- IoU argmax, division-free, ONE ds_read_b128 per GT shared by
    //      both anchors. best kept as fraction (n/d); n_j*d > n*d_j
    //      replaces rcp+mul per GT. ----
    float n0 = -1.0f, d0 = 1.0f, n1 = -1.0f, d1 = 1.0f;
    int   bi0 = 0, bi1 = 0;
    #pragma unroll 4
    for (int j = 0; j < M; ++j) {
        const float4 g  = s_gbox[j];
        const float  ab = (g.z - g.x) * (g.w - g.y);   // 2 VALU, not a b32 read
        {
            const float iw = fmaxf(fminf(av0.z, g.z) - fmaxf(av0.x, g.x), 0.f);
            const float ih = fmaxf(fminf(av0.w, g.w) - fmaxf(av0.y, g.y), 0.f);
            const float inter = iw * ih;
            const float ua = fmaxf(area0 + ab - inter, 1e-8f);
            if (inter * d0 > n0 * ua) { n0 = inter; d0 = ua; bi0 = j; }
        }
        {
            const float iw = fmaxf(fminf(av1.z, g.z) - fmaxf(av1.x, g.x), 0.f);
            const float ih = fmaxf(fminf(av1.w, g.w) - fmaxf(av1.y, g.y), 0.f);
            const float inter = iw * ih;
            const float ua = fmaxf(area1 + ab - inter, 1e-8f);
            if (inter * d1 > n1 * ua) { n1 = inter; d1 = ua; bi1 = j; }
        }
    }

    // ---- per-anchor tail, sequential (R0 structure: cls loaded AFTER the
    //      IoU loop; R3 proved prefetching it earlier doesn't help). ----
    #pragma unroll
    for (int s = 0; s < 2; ++s) {
        const bool  ok = s == 0 ? ok0 : ok1;
        if (!ok) continue;
        const int   a  = s == 0 ? a0  : a1;
        const float4 av = s == 0 ? av0 : av1;
        const float n_b = s == 0 ? n0 : n1;
        const float d_b = s == 0 ? d0 : d1;
        const int   bi  = s == 0 ? bi0 : bi1;

        const float bv = n_b * __frcp_rn(d_b);    // value only for thresholds
        const bool pos    = bv >= 0.5f;
        const bool ignore = (bv >= 0.4f) && !pos;
        const int  lbl    = s_glbl[bi];           // in [0,19] whenever pos

        // ---- classification focal loss: negative-form sum in log2 space.
        //      cls = 0.8*ln2 * sum(p^1.5 * -log2(1-p)) (+ pos correction). ----
        if (!ignore) {
            const float* cp = cls + ((size_t)b * A + a) * C;
            float sum = 0.f;                      // in log2 units
            float p_t = 0.5f;                     // label-class prob (pos only)
            #pragma unroll
            for (int k = 0; k < C / 4; ++k) {
                const float4 v = *(const float4*)(cp + k * 4);
                const float pv4[4] = {v.x, v.y, v.z, v.w};
                #pragma unroll
                for (int u = 0; u < 4; ++u) {
                    const int c = k * 4 + u;
                    const float p = fminf(fmaxf(pv4[u], 1e-8f), 1.0f - 1e-8f);
                    sum += p * __builtin_amdgcn_sqrtf(p) * (-__log2f(1.0f - p));
                    p_t = (c == lbl) ? p : p_t;   // one cndmask per class
                }
            }
            sum *= 0.8f;
            if (pos) {                            // swap in the label-class term
                const float q = 1.0f - p_t;
                sum -= 0.8f * p_t * __builtin_amdgcn_sqrtf(p_t) * (-__log2f(q));
                sum += 0.2f * q   * __builtin_amdgcn_sqrtf(q)   * (-__log2f(p_t));
            }
            clsSum += sum * LN2F;
        }

        // ---- regression smooth-L1 (positives only) ----
        if (pos) {
            posf += 1.0f;
            const float aw  = av.z - av.x;
            const float ah  = av.w - av.y;
            const float acx = av.x + 0.5f * aw;
            const float acy = av.y + 0.5f * ah;
            const float4 g = s_gbox[bi];
            const float gwr = g.z - g.x, ghr = g.w - g.y;
            const float gcx = g.x + 0.5f * gwr, gcy = g.y + 0.5f * ghr;
            const float gw = fmaxf(gwr, 1.f), gh = fmaxf(ghr, 1.f);
            float rt[4];
            rt[0] = ((gcx - acx) / aw) / 0.1f;
            rt[1] = ((gcy - acy) / ah) / 0.1f;
            rt[2] = __logf(gw / aw) / 0.2f;
            rt[3] = __logf(gh / ah) / 0.2f;
            const float4 rv = *(const float4*)(reg + ((size_t)b * A + a) * 4);
            const float rr[4] = {rv.x, rv.y, rv.z, rv.w};
            #pragma unroll
            for (int u = 0; u < 4; ++u) {
                const float d = fabsf(rt[u] - rr[u]);
                regSum += (d <= (float)(1.0 / 9.0)) ? (4.5f * d * d)
                                                    : (d - (float)(0.5 / 9.0));
            }
        }
    }

    // ---- block reduce: wave shuffle -> cross-wave LDS -> ONE plain store ----
    #pragma unroll
    for (int off = 32; off > 0; off >>= 1) {
        clsSum += __shfl_down(clsSum, off, 64);
        regSum += __shfl_down(regSum, off, 64);
        posf   += __shfl_down(posf,   off, 64);
    }
    const int wave = tid >> 6;          // 0..1
    const int lane = tid & 63;
    if (lane == 0) {
        s_red[wave*3+0] = clsSum;
        s_red[wave*3+1] = regSum;
        s_red[wave*3+2] = posf;
    }
    __syncthreads();
    if (tid == 0) {
        float cs = 0.f, rs = 0.f, ps = 0.f;
        #pragma unroll
        for (int w2 = 0; w2 < 2; ++w2) {
            cs += s_red[w2*3+0];
            rs += s_red[w2*3+1];
            ps += s_red[w2*3+2];
        }
        const size_t slot = ((size_t)b * gridDim.x + blockIdx.x) * 4;
        *(float4*)(part + slot) = make_float4(cs, rs, ps, 0.f);
    }
}

// Tree-reduce the B x nblk partial triplets + final normalization.
// 1024 threads: 128 threads per image (B=8).
__global__ __launch_bounds__(1024) void focal_final(
    const float* __restrict__ part,
    const float* __restrict__ ann,
    float* __restrict__ out, int B, int nblk)
{
    __shared__ float s_sum[8][2][3];   // [image][wave-in-group][{cls,reg,pos}]
    __shared__ float s_f[256];
    __shared__ float s_c[8], s_r[8];

    const int tid = threadIdx.x;
    const int g   = tid >> 7;          // image 0..7
    const int i   = tid & 127;

    float cs = 0.f, rs = 0.f, ps = 0.f;
    if (g < B) {
        for (int bx = i; bx < nblk; bx += 128) {
            const float4 v = *(const float4*)(part + ((size_t)g * nblk + bx) * 4);
            cs += v.x; rs += v.y; ps += v.z;
        }
    }
    #pragma unroll
    for (int off = 32; off > 0; off >>= 1) {
        cs += __shfl_down(cs, off, 64);
        rs += __shfl_down(rs, off, 64);
        ps += __shfl_down(ps, off, 64);
    }
    const int lane = tid & 63;
    const int wv   = (tid >> 6) & 1;   // wave within the 128-thread group
    if (lane == 0 && g < 8) {
        s_sum[g][wv][0] = cs; s_sum[g][wv][1] = rs; s_sum[g][wv][2] = ps;
    }

    // GT validity flags in parallel (B*M = 256)
    if (tid < 256) {
        float f = 0.f;
        if (tid < B * M) {
            const int bb = tid >> 5, j = tid & 31;
            f = (ann[(size_t)bb * M * 5 + (size_t)j * 5 + 4] != -1.0f) ? 1.f : 0.f;
        }
        s_f[tid] = f;
    }
    __syncthreads();

    if (tid < B) {
        const float S  = s_sum[tid][0][0] + s_sum[tid][1][0];
        const float R  = s_sum[tid][0][1] + s_sum[tid][1][1];
        const float np = s_sum[tid][0][2] + s_sum[tid][1][2];
        float nv = 0.f;
        #pragma unroll
        for (int j = 0; j < M; ++j) nv += s_f[tid * M + j];
        float cl = S / fmaxf(np, 1.f);
        float rl = (np > 0.f) ? R / fmaxf(4.f * np, 1.f) : 0.f;
        if (nv == 0.f) { cl = 0.f; rl = 0.f; }
        s_c[tid] = cl; s_r[tid] = rl;
    }
    __syncthreads();

    if (tid == 0) {
        float ca = 0.f, ra = 0.f;
        for (int b2 = 0; b2 < B; ++b2) { ca += s_c[b2]; ra += s_r[b2]; }
        out[0] = ca / (float)B;
        out[1] = ra / (float)B;
    }
}

extern "C" void kernel_launch(void* const* d_in, const int* in_sizes, int n_in,
                              void* d_out, int out_size, void* d_ws, size_t ws_size,
                              hipStream_t stream) {
    const float* cls = (const float*)d_in[0];   // [B,A,C]
    const float* reg = (const float*)d_in[1];   // [B,A,4]
    const float* anc = (const float*)d_in[2];   // [1,A,4]
    const float* ann = (const float*)d_in[3];   // [B,M,5]
    const int A = in_sizes[2] / 4;
    const int B = in_sizes[3] / (M * 5);
    const int nblk = (A + 255) / 256;           // 256 anchors per block, 469 blocks

    float* part = (float*)d_ws;   // B*nblk*4 floats (~60 KB); every slot is
                                  // written by focal_main, so no memset needed.

    dim3 grid(nblk, B);
    focal_main<<<grid, dim3(128), 0, stream>>>(cls, reg, anc, ann, part, A);
    focal_final<<<1, dim3(1024), 0, stream>>>(part, ann, (float*)d_out, B, nblk);
}

// Round 5
// 128.737 us; speedup vs baseline: 1.0112x; 1.0112x over previous
//
#include <hip/hip_runtime.h>
#include <math.h>

constexpr int C = 20;   // classes
constexpr int M = 32;   // max GT per image
#define LN2F 0.69314718055994530942f

// FINAL (R5 revert to R0, the session's measured best: 127.4 us).
// Session ledger — every structural alternative was measured and regressed:
//   R0 127.4  ds_read IoU loop, KPA=1, cls after IoU, max TLP  <- BEST
//   R1 134.2  readlane IoU + KPA=2 + 2x cls prefetch (VGPR cliff)
//   R2 135.6  readlane IoU + GT compaction + 1x prefetch (readlane hazards)
//   R3 129.0  R0 + cls prefetch only (+1.6 us: not load-latency-stalled)
//   R4 130.2  KPA=2 ds_read sharing, half the waves (-TLP > +amortization)
// Conclusion: focal_main is TLP/latency-bound and self-hiding at 15008 waves;
// floors (~13 us HBM + ~9 us VALU, overlapped) leave no lever that doesn't
// cost occupancy. Timed window is dominated by 2 harness re-poison fills
// (~93 us at 82% HBM peak) which no kernel change can touch.
//
// d_ws layout: part[(b*nblk + bx)*4 + {0,1,2}] = {cls_sum, reg_sum, num_pos}
// per block. Plain stores — NO atomics (device-scope atomicAdd to 2 cache
// lines serializes at ~28 cyc each; 11K atomics == 135 us).
__global__ __launch_bounds__(256) void focal_main(
    const float* __restrict__ cls,   // [B,A,C]
    const float* __restrict__ reg,   // [B,A,4]
    const float* __restrict__ anc,   // [A,4]
    const float* __restrict__ ann,   // [B,M,5]
    float* __restrict__ part,
    int A)
{
    __shared__ float4 s_gbox[M];   // {x1,y1,x2,y2}; invalid GT -> zero box (iou=0)
    __shared__ float  s_garea[M];
    __shared__ int    s_glbl[M];
    __shared__ float  s_red[4 * 3];

    const int b   = blockIdx.y;
    const int tid = threadIdx.x;

    // ---- stage annotations (validity folded: 2 LDS reads/GT in IoU loop) ----
    if (tid < M) {
        const float* ap = ann + (size_t)b * M * 5 + (size_t)tid * 5;
        float x1 = ap[0], y1 = ap[1], x2 = ap[2], y2 = ap[3];
        const float lb = ap[4];
        s_glbl[tid] = (int)lb;
        if (lb == -1.0f) { x1 = 0.f; y1 = 0.f; x2 = 0.f; y2 = 0.f; }
        s_gbox[tid]  = make_float4(x1, y1, x2, y2);
        s_garea[tid] = (x2 - x1) * (y2 - y1);
    }
    __syncthreads();

    const int a = blockIdx.x * 256 + tid;

    float clsSum = 0.f, regSum = 0.f, posf = 0.f;

    if (a < A) {
        const float4 av = *(const float4*)(anc + (size_t)a * 4);
        const float aw  = av.z - av.x;
        const float ah  = av.w - av.y;
        const float acx = av.x + 0.5f * aw;
        const float acy = av.y + 0.5f * ah;
        const float area_a = aw * ah;

        // ---- IoU argmax, division-free: best kept as fraction (n_b/d_b).
        //      n_j*d_b > n_b*d_j replaces rcp+mul per GT (one rcp per anchor).
        //      unroll 8: full 32-unroll batched ds_reads -> VGPR 80, occ 25%. ----
        float n_b = -1.0f, d_b = 1.0f;
        int   bi = 0;
        #pragma unroll 8
        for (int j = 0; j < M; ++j) {
            const float4 g  = s_gbox[j];
            const float  ab = s_garea[j];
            const float iw = fmaxf(fminf(av.z, g.z) - fmaxf(av.x, g.x), 0.f);
            const float ih = fmaxf(fminf(av.w, g.w) - fmaxf(av.y, g.y), 0.f);
            const float inter = iw * ih;
            const float ua = fmaxf(area_a + ab - inter, 1e-8f);
            if (inter * d_b > n_b * ua) { n_b = inter; d_b = ua; bi = j; }
        }
        const float bv = n_b * __frcp_rn(d_b);    // value only for thresholds
        const bool pos    = bv >= 0.5f;
        const bool ignore = (bv >= 0.4f) && !pos;
        const int  lbl    = s_glbl[bi];           // in [0,19] whenever pos

        // ---- classification focal loss: negative-form sum in log2 space.
        //      cls = 0.8*ln2 * sum(p^1.5 * -log2(1-p)) (+ pos correction). ----
        if (!ignore) {
            const float* cp = cls + ((size_t)b * A + a) * C;
            float sum = 0.f;                      // in log2 units
            float p_t = 0.5f;                     // label-class prob (pos only)
            #pragma unroll
            for (int k = 0; k < C / 4; ++k) {
                const float4 v = *(const float4*)(cp + k * 4);
                const float pv4[4] = {v.x, v.y, v.z, v.w};
                #pragma unroll
                for (int u = 0; u < 4; ++u) {
                    const int c = k * 4 + u;
                    const float p = fminf(fmaxf(pv4[u], 1e-8f), 1.0f - 1e-8f);
                    sum += p * __builtin_amdgcn_sqrtf(p) * (-__log2f(1.0f - p));
                    p_t = (c == lbl) ? p : p_t;   // one cndmask per class
                }
            }
            sum *= 0.8f;
            if (pos) {                            // swap in the label-class term
                const float q = 1.0f - p_t;
                sum -= 0.8f * p_t * __builtin_amdgcn_sqrtf(p_t) * (-__log2f(q));
                sum += 0.2f * q   * __builtin_amdgcn_sqrtf(q)   * (-__log2f(p_t));
            }
            clsSum = sum * LN2F;
        }

        // ---- regression smooth-L1 (positives only) ----
        if (pos) {
            posf = 1.0f;
            const float4 g = s_gbox[bi];
            const float gwr = g.z - g.x, ghr = g.w - g.y;
            const float gcx = g.x + 0.5f * gwr, gcy = g.y + 0.5f * ghr;
            const float gw = fmaxf(gwr, 1.f), gh = fmaxf(ghr, 1.f);
            float rt[4];
            rt[0] = ((gcx - acx) / aw) / 0.1f;
            rt[1] = ((gcy - acy) / ah) / 0.1f;
            rt[2] = __logf(gw / aw) / 0.2f;
            rt[3] = __logf(gh / ah) / 0.2f;
            const float4 rv = *(const float4*)(reg + ((size_t)b * A + a) * 4);
            const float rr[4] = {rv.x, rv.y, rv.z, rv.w};
            #pragma unroll
            for (int u = 0; u < 4; ++u) {
                const float d = fabsf(rt[u] - rr[u]);
                regSum += (d <= (float)(1.0 / 9.0)) ? (4.5f * d * d)
                                                    : (d - (float)(0.5 / 9.0));
            }
        }
    }

    // ---- block reduce: wave shuffle -> cross-wave LDS -> ONE plain store ----
    #pragma unroll
    for (int off = 32; off > 0; off >>= 1) {
        clsSum += __shfl_down(clsSum, off, 64);
        regSum += __shfl_down(regSum, off, 64);
        posf   += __shfl_down(posf,   off, 64);
    }
    const int wave = tid >> 6;
    const int lane = tid & 63;
    if (lane == 0) {
        s_red[wave*3+0] = clsSum;
        s_red[wave*3+1] = regSum;
        s_red[wave*3+2] = posf;
    }
    __syncthreads();
    if (tid == 0) {
        float cs = 0.f, rs = 0.f, ps = 0.f;
        #pragma unroll
        for (int w2 = 0; w2 < 4; ++w2) {
            cs += s_red[w2*3+0];
            rs += s_red[w2*3+1];
            ps += s_red[w2*3+2];
        }
        const size_t slot = ((size_t)b * gridDim.x + blockIdx.x) * 4;
        *(float4*)(part + slot) = make_float4(cs, rs, ps, 0.f);
    }
}

// Tree-reduce the B x nblk partial triplets + final normalization.
// 1024 threads: 128 threads per image (B=8).
__global__ __launch_bounds__(1024) void focal_final(
    const float* __restrict__ part,
    const float* __restrict__ ann,
    float* __restrict__ out, int B, int nblk)
{
    __shared__ float s_sum[8][2][3];   // [image][wave-in-group][{cls,reg,pos}]
    __shared__ float s_f[256];
    __shared__ float s_c[8], s_r[8];

    const int tid = threadIdx.x;
    const int g   = tid >> 7;          // image 0..7
    const int i   = tid & 127;

    float cs = 0.f, rs = 0.f, ps = 0.f;
    if (g < B) {
        for (int bx = i; bx < nblk; bx += 128) {
            const float4 v = *(const float4*)(part + ((size_t)g * nblk + bx) * 4);
            cs += v.x; rs += v.y; ps += v.z;
        }
    }
    #pragma unroll
    for (int off = 32; off > 0; off >>= 1) {
        cs += __shfl_down(cs, off, 64);
        rs += __shfl_down(rs, off, 64);
        ps += __shfl_down(ps, off, 64);
    }
    const int lane = tid & 63;
    const int wv   = (tid >> 6) & 1;   // wave within the 128-thread group
    if (lane == 0 && g < 8) {
        s_sum[g][wv][0] = cs; s_sum[g][wv][1] = rs; s_sum[g][wv][2] = ps;
    }

    // GT validity flags in parallel (B*M = 256)
    if (tid < 256) {
        float f = 0.f;
        if (tid < B * M) {
            const int bb = tid >> 5, j = tid & 31;
            f = (ann[(size_t)bb * M * 5 + (size_t)j * 5 + 4] != -1.0f) ? 1.f : 0.f;
        }
        s_f[tid] = f;
    }
    __syncthreads();

    if (tid < B) {
        const float S  = s_sum[tid][0][0] + s_sum[tid][1][0];
        const float R  = s_sum[tid][0][1] + s_sum[tid][1][1];
        const float np = s_sum[tid][0][2] + s_sum[tid][1][2];
        float nv = 0.f;
        #pragma unroll
        for (int j = 0; j < M; ++j) nv += s_f[tid * M + j];
        float cl = S / fmaxf(np, 1.f);
        float rl = (np > 0.f) ? R / fmaxf(4.f * np, 1.f) : 0.f;
        if (nv == 0.f) { cl = 0.f; rl = 0.f; }
        s_c[tid] = cl; s_r[tid] = rl;
    }
    __syncthreads();

    if (tid == 0) {
        float ca = 0.f, ra = 0.f;
        for (int b2 = 0; b2 < B; ++b2) { ca += s_c[b2]; ra += s_r[b2]; }
        out[0] = ca / (float)B;
        out[1] = ra / (float)B;
    }
}

extern "C" void kernel_launch(void* const* d_in, const int* in_sizes, int n_in,
                              void* d_out, int out_size, void* d_ws, size_t ws_size,
                              hipStream_t stream) {
    const float* cls = (const float*)d_in[0];   // [B,A,C]
    const float* reg = (const float*)d_in[1];   // [B,A,4]
    const float* anc = (const float*)d_in[2];   // [1,A,4]
    const float* ann = (const float*)d_in[3];   // [B,M,5]
    const int A = in_sizes[2] / 4;
    const int B = in_sizes[3] / (M * 5);
    const int nblk = (A + 255) / 256;

    float* part = (float*)d_ws;   // B*nblk*4 floats (~60 KB); every slot is
                                  // written by focal_main, so no memset needed.

    dim3 grid(nblk, B);
    focal_main<<<grid, dim3(256), 0, stream>>>(cls, reg, anc, ann, part, A);
    focal_final<<<1, dim3(1024), 0, stream>>>(part, ann, (float*)d_out, B, nblk);
}